// Round 20
// baseline (167.053 us; speedup 1.0000x reference)
//
#include <hip/hip_runtime.h>
#include <hip/hip_bf16.h>

#define BB 2
#define CC 512
#define GG 32
#define NN 4096
#define EPSV 1e-6f

typedef __attribute__((ext_vector_type(4))) float f32x4;
typedef __attribute__((ext_vector_type(8))) short s16x8;
typedef __attribute__((ext_vector_type(4))) short s16x4;

__device__ __forceinline__ ushort f2bf(float f){
  union { float f; unsigned u; } v; v.f = f;
  unsigned r = v.u + 0x7fffu + ((v.u >> 16) & 1u);
  return (ushort)(r >> 16);
}
__device__ __forceinline__ short f2bfs(float f){ return (short)f2bf(f); }
__device__ __forceinline__ float b2f(ushort u){
  union { unsigned u; float f; } v; v.u = ((unsigned)u) << 16; return v.f;
}

__device__ __forceinline__ f32x4 mfma16(s16x8 a, s16x8 b, f32x4 c){
  return __builtin_amdgcn_mfma_f32_16x16x32_bf16(a, b, c, 0, 0, 0);
}

#define GLOAD_LDS16(g, l) __builtin_amdgcn_global_load_lds( \
    (const __attribute__((address_space(1))) void*)(g),     \
    (__attribute__((address_space(3))) void*)(l), 16, 0, 0)

// ---------------- prep: weight fp32->bf16 (blocks 256..511) + GN stats stage1 (blocks 0..255) ----------------
__global__ __launch_bounds__(256) void k_prep(const float* __restrict__ wq, const float* __restrict__ wk,
                                              const float* __restrict__ wv, const float* __restrict__ wp,
                                              ushort* __restrict__ wbf,
                                              const float* __restrict__ x, float* __restrict__ pstat){
  if (blockIdx.x >= 256){
    int idx = (blockIdx.x - 256) * 256 + threadIdx.x;
    const float* srcs[4] = {wq, wk, wv, wp};
    #pragma unroll
    for (int m = 0; m < 4; m++){
      float4 v = reinterpret_cast<const float4*>(srcs[m])[idx];
      ushort4 o; o.x = f2bf(v.x); o.y = f2bf(v.y); o.z = f2bf(v.z); o.w = f2bf(v.w);
      reinterpret_cast<ushort4*>(wbf + (size_t)m * CC * CC)[idx] = o;
    }
    return;
  }
  int blk = blockIdx.x;   // 0..255, chunk of 16384 floats
  const float* p = x + (size_t)blk * 16384;
  float s = 0.f, ss = 0.f;
  for (int i = threadIdx.x; i < 4096; i += 256){
    float4 v = reinterpret_cast<const float4*>(p)[i];
    s  += v.x + v.y + v.z + v.w;
    ss += v.x*v.x + v.y*v.y + v.z*v.z + v.w*v.w;
  }
  #pragma unroll
  for (int off = 32; off; off >>= 1){ s += __shfl_down(s, off); ss += __shfl_down(ss, off); }
  __shared__ float rs_[4], rss_[4];
  int w = threadIdx.x >> 6, lane = threadIdx.x & 63;
  if (lane == 0){ rs_[w] = s; rss_[w] = ss; }
  __syncthreads();
  if (threadIdx.x == 0){
    pstat[blk * 2 + 0] = rs_[0] + rs_[1] + rs_[2] + rs_[3];
    pstat[blk * 2 + 1] = rss_[0] + rss_[1] + rss_[2] + rss_[3];
  }
}

// ---------------- GN apply + transpose, stats stage2 folded ----------------
__global__ __launch_bounds__(256) void k_gn_apply(const float* __restrict__ x, const float* __restrict__ gsc,
                                                  const float* __restrict__ gbi, const float* __restrict__ pstat,
                                                  ushort* __restrict__ hf){
  __shared__ ushort tr[32][520];
  __shared__ float stl[64];   // 32 groups x {mean, rstd} for this b
  int b = blockIdx.y;
  int nb = blockIdx.x * 32;
  int t = threadIdx.x;
  if (t < 32){
    float s = 0.f, ss = 0.f;
    #pragma unroll
    for (int k = 0; k < 4; k++){
      s  += pstat[(b * 128 + t * 4 + k) * 2 + 0];
      ss += pstat[(b * 128 + t * 4 + k) * 2 + 1];
    }
    float inv = 1.0f / (16.0f * NN);
    float mean = s * inv;
    float var = ss * inv - mean * mean;
    stl[t * 2 + 0] = mean;
    stl[t * 2 + 1] = rsqrtf(var + EPSV);
  }
  __syncthreads();
  int n = t & 31, cr = t >> 5;
  const float* xb = x + (size_t)b * CC * NN;
  for (int c0 = 0; c0 < CC; c0 += 8){
    int c = c0 + cr;
    float mean = stl[(c >> 4) * 2 + 0];
    float rstd = stl[(c >> 4) * 2 + 1];
    float v = xb[(size_t)c * NN + nb + n];
    tr[n][c] = f2bf((v - mean) * rstd * gsc[c] + gbi[c]);
  }
  __syncthreads();
  ushort* out = hf + ((size_t)b * NN + nb) * CC;
  int c8 = (t & 63) * 8;
  int nrow0 = t >> 6;
  #pragma unroll
  for (int i = 0; i < 8; i++){
    int nr = nrow0 + i * 4;
    *reinterpret_cast<s16x8*>(&out[(size_t)nr * CC + c8]) =
      *reinterpret_cast<const s16x8*>(&tr[nr][c8]);
  }
}

// ---------------- fused QKV GEMM v3: 64o x 128n tile, BK=32, dbuf; XCD-chunked (ob fastest) ----------------
__global__ __launch_bounds__(256, 3) void k_gemm_qkv2(const ushort* __restrict__ W, const ushort* __restrict__ Bt,
                                                      const float* __restrict__ bq, const float* __restrict__ bk,
                                                      const float* __restrict__ bv,
                                                      ushort* __restrict__ qo, ushort* __restrict__ ko,
                                                      ushort* __restrict__ vo, float rs){
  __shared__ __align__(16) char smem[40960];
  __shared__ float bl[3][64];
  // XCD swizzle: same (nb,b) per XCD, ob fastest -> hf n-slice L2-resident across 8 ob-blocks
  int lin = blockIdx.x + 32 * blockIdx.y + 256 * blockIdx.z;   // 0..511
  int tt0 = (lin & 7) * 64 + (lin >> 3);
  int obk = tt0 & 7;
  int rest = tt0 >> 3;          // 0..63
  int b = rest >> 5;
  int ob = obk * 64, nb = (rest & 31) * 128;
  int t = threadIdx.x, w = t >> 6, l = t & 63;
  int lr = l & 15, lk = l >> 4;
  int wo = (w >> 1) * 32, wn = (w & 1) * 64;
  if (t < 64){ bl[0][t] = bq[ob + t]; bl[1][t] = bk[ob + t]; bl[2][t] = bv[ob + t]; }
  const ushort* Bp = Bt + ((size_t)b * NN + nb) * CC;
  const ushort* Wp = W + (size_t)ob * CC;
  int srow = l >> 2;
  int schunk = (l & 3) ^ ((l >> 2) & 3) ^ ((l >> 4) & 3);
  int xs = (lk ^ (lr & 3) ^ ((lr >> 2) & 3)) * 8;

#define STAGE_QKV(BUF, K0)                                                               \
  {                                                                                      \
    ushort* As_ = (ushort*)(smem + (BUF) * 20480);                                       \
    ushort* Bs_ = As_ + 6144;                                                            \
    _Pragma("unroll")                                                                    \
    for (int tt = 0; tt < 5; tt++){                                                      \
      int inst = w * 5 + tt;                                                             \
      if (inst < 12){                                                                    \
        int m = inst >> 2, sub = inst & 3;                                               \
        const ushort* src = Wp + (size_t)m * CC * CC + (size_t)(sub * 16 + srow) * CC + (K0) + schunk * 8; \
        GLOAD_LDS16(src, As_ + m * 2048 + sub * 512);                                    \
      } else {                                                                           \
        int q = inst - 12;                                                               \
        const ushort* src = Bp + (size_t)(q * 16 + srow) * CC + (K0) + schunk * 8;       \
        GLOAD_LDS16(src, Bs_ + q * 512);                                                 \
      }                                                                                  \
    }                                                                                    \
  }

  f32x4 acc[3][2][4] = {};
  STAGE_QKV(0, 0)
  __syncthreads();
  for (int s16 = 0; s16 < 16; s16++){
    if (s16 < 15) STAGE_QKV((s16 + 1) & 1, (s16 + 1) * 32)
    const ushort* As = (const ushort*)(smem + (s16 & 1) * 20480);
    const ushort* Bs = As + 6144;
    s16x8 bf[4];
    #pragma unroll
    for (int sn = 0; sn < 4; sn++)
      bf[sn] = *(const s16x8*)&Bs[(wn + sn * 16 + lr) * 32 + xs];
    #pragma unroll
    for (int m = 0; m < 3; m++){
      s16x8 a0 = *(const s16x8*)&As[m * 2048 + (wo + lr) * 32 + xs];
      s16x8 a1 = *(const s16x8*)&As[m * 2048 + (wo + 16 + lr) * 32 + xs];
      #pragma unroll
      for (int sn = 0; sn < 4; sn++){
        acc[m][0][sn] = mfma16(a0, bf[sn], acc[m][0][sn]);
        acc[m][1][sn] = mfma16(a1, bf[sn], acc[m][1][sn]);
      }
    }
    __syncthreads();
  }
#undef STAGE_QKV
  #pragma unroll
  for (int m = 0; m < 2; m++){
    ushort* dst = (m == 0) ? qo : ko;
    float scl = (m == 0) ? rs : 1.0f;
    #pragma unroll
    for (int so = 0; so < 2; so++)
      #pragma unroll
      for (int sn = 0; sn < 4; sn++){
        int o0 = wo + so * 16 + lk * 4;
        int n  = nb + wn + sn * 16 + lr;
        s16x4 pv;
        #pragma unroll
        for (int r = 0; r < 4; r++) pv[r] = f2bfs((acc[m][so][sn][r] + bl[m][o0 + r]) * scl);
        *reinterpret_cast<s16x4*>(&dst[((size_t)b * NN + n) * CC + ob + o0]) = pv;
      }
  }
  ushort* Ve = (ushort*)smem;   // [64][136]
  #pragma unroll
  for (int so = 0; so < 2; so++)
    #pragma unroll
    for (int sn = 0; sn < 4; sn++){
      int o0 = wo + so * 16 + lk * 4;
      int ncl = wn + sn * 16 + lr;
      #pragma unroll
      for (int r = 0; r < 4; r++) Ve[(o0 + r) * 136 + ncl] = f2bf(acc[2][so][sn][r] + bl[2][o0 + r]);
    }
  __syncthreads();
  {
    int row = t >> 2, cs = (t & 3) * 32;
    ushort* dst = &vo[((size_t)b * CC + ob + row) * NN + nb + cs];
    #pragma unroll
    for (int k = 0; k < 4; k++)
      *(s16x8*)&dst[k * 8] = *(const s16x8*)&Ve[row * 136 + cs + k * 8];
  }
}

// ---------------- S GEMM v6: 256x256, BK=64, 4-phase interleaved schedule ----------------
__global__ __launch_bounds__(512, 2) void k_gemm_s(const ushort* __restrict__ qt, const ushort* __restrict__ kt,
                                                   ushort* __restrict__ P, float* __restrict__ part){
  extern __shared__ __align__(16) char smem[];   // Kbuf[2][32KB] @0, Qbuf[2][32KB] @64KB
  int lin = blockIdx.x + 16 * blockIdx.y + 256 * blockIdx.z;   // 0..511
  int tt0 = (lin & 7) * 64 + (lin >> 3);
  int jblk = tt0 & 15;
  int pair = tt0 >> 4;
  int b = pair >> 4;
  int j0 = jblk * 256, i0 = (pair & 15) * 256;
  int t = threadIdx.x, w = t >> 6, l = t & 63;
  int lr = l & 15, lk = l >> 4;
  int wj2 = w >> 2, wi4 = w & 3;
  const ushort* kb = kt + ((size_t)b * NN + j0) * CC;
  const ushort* qb = qt + ((size_t)b * NN + i0) * CC;
  int srow = l >> 3;
  int schunk = (l & 7) ^ srow;

#define STAGE_KH(BUF, K0, H)                                                      \
  {                                                                               \
    ushort* D = (ushort*)(smem + (BUF) * 32768);                                  \
    _Pragma("unroll")                                                             \
    for (int tt = 0; tt < 2; tt++){                                               \
      int g = (H) * 16 + w * 2 + tt;                                              \
      const ushort* src = kb + (size_t)(g * 8 + srow) * CC + (K0) + schunk * 8;   \
      GLOAD_LDS16(src, D + g * 512);                                              \
    }                                                                             \
  }
#define STAGE_QH(BUF, K0, H)                                                      \
  {                                                                               \
    ushort* D = (ushort*)(smem + 65536 + (BUF) * 32768);                          \
    _Pragma("unroll")                                                             \
    for (int tt = 0; tt < 2; tt++){                                               \
      int g = (H) * 16 + w * 2 + tt;                                              \
      const ushort* src = qb + (size_t)(g * 8 + srow) * CC + (K0) + schunk * 8;   \
      GLOAD_LDS16(src, D + g * 512);                                              \
    }                                                                             \
  }
#define PHASE(SJ, STAGE_CODE)                                                     \
  {                                                                               \
    s16x8 a00 = *(const s16x8*)&Ks[(wj2 * 128 + (SJ) * 16 + lr) * 64 + xs0];      \
    s16x8 a01 = *(const s16x8*)&Ks[(wj2 * 128 + (SJ) * 16 + lr) * 64 + xs1];      \
    s16x8 a10 = *(const s16x8*)&Ks[(wj2 * 128 + ((SJ) + 1) * 16 + lr) * 64 + xs0];\
    s16x8 a11 = *(const s16x8*)&Ks[(wj2 * 128 + ((SJ) + 1) * 16 + lr) * 64 + xs1];\
    STAGE_CODE                                                                    \
    __builtin_amdgcn_s_barrier();                                                 \
    asm volatile("s_waitcnt lgkmcnt(0)" ::: "memory");                            \
    __builtin_amdgcn_sched_barrier(0);                                            \
    __builtin_amdgcn_s_setprio(1);                                                \
    _Pragma("unroll")                                                             \
    for (int si = 0; si < 4; si++){                                               \
      acc[SJ][si]       = mfma16(a00, bq[si][0], acc[SJ][si]);                    \
      acc[SJ][si]       = mfma16(a01, bq[si][1], acc[SJ][si]);                    \
      acc[(SJ) + 1][si] = mfma16(a10, bq[si][0], acc[(SJ) + 1][si]);              \
      acc[(SJ) + 1][si] = mfma16(a11, bq[si][1], acc[(SJ) + 1][si]);              \
    }                                                                             \
    __builtin_amdgcn_s_setprio(0);                                                \
    __builtin_amdgcn_s_barrier();                                                 \
  }

  f32x4 acc[8][4] = {};
  STAGE_KH(0, 0, 0)
  STAGE_KH(0, 0, 1)
  STAGE_QH(0, 0, 0)
  STAGE_QH(0, 0, 1)
  STAGE_QH(1, 64, 0)
  STAGE_QH(1, 64, 1)
  #pragma unroll
  for (int s8 = 0; s8 < 8; s8++){
    const int tau = s8 & 1;
    const ushort* Ks = (const ushort*)(smem + tau * 32768);
    const ushort* Qs = (const ushort*)(smem + 65536 + tau * 32768);
    if (s8 < 7){ asm volatile("s_waitcnt vmcnt(4)" ::: "memory"); }
    else       { asm volatile("s_waitcnt vmcnt(0)" ::: "memory"); }
    __builtin_amdgcn_s_barrier();
    __builtin_amdgcn_sched_barrier(0);
    int xs0 = (lk ^ (lr & 7)) * 8;
    int xs1 = ((4 + lk) ^ (lr & 7)) * 8;
    s16x8 bq[4][2];
    #pragma unroll
    for (int si = 0; si < 4; si++){
      bq[si][0] = *(const s16x8*)&Qs[(wi4 * 64 + si * 16 + lr) * 64 + xs0];
      bq[si][1] = *(const s16x8*)&Qs[(wi4 * 64 + si * 16 + lr) * 64 + xs1];
    }
    PHASE(0, if (s8 < 7) STAGE_KH(tau ^ 1, (s8 + 1) * 64, 0))
    PHASE(2, if (s8 < 7) STAGE_KH(tau ^ 1, (s8 + 1) * 64, 1))
    PHASE(4, if (s8 < 6) STAGE_QH(tau, (s8 + 2) * 64, 0))
    PHASE(6, if (s8 < 6) STAGE_QH(tau, (s8 + 2) * 64, 1))
  }
#undef PHASE
#undef STAGE_KH
#undef STAGE_QH
  ushort* Pe = (ushort*)smem;   // [128 i][264 j] per pass
  float rsum[4] = {0.f, 0.f, 0.f, 0.f};
  #pragma unroll
  for (int pass = 0; pass < 2; pass++){
    if ((wi4 >> 1) == pass){
      #pragma unroll
      for (int sj = 0; sj < 8; sj++)
        #pragma unroll
        for (int si = 0; si < 4; si++){
          int il = (wi4 & 1) * 64 + si * 16 + lr;
          int jl = wj2 * 128 + sj * 16 + lk * 4;
          s16x4 pk;
          #pragma unroll
          for (int r = 0; r < 4; r++){
            float e = __builtin_amdgcn_exp2f(acc[sj][si][r]);
            pk[r] = f2bfs(e);
            rsum[si] += e;
          }
          *(s16x4*)&Pe[il * 264 + jl] = pk;
        }
    }
    __syncthreads();
    {
      int row = t >> 2, cs = (t & 3) * 64;
      ushort* dst = P + ((size_t)b * NN + i0 + pass * 128 + row) * NN + j0 + cs;
      #pragma unroll
      for (int k = 0; k < 8; k++)
        *(s16x8*)&dst[k * 8] = *(const s16x8*)&Pe[row * 264 + cs + k * 8];
    }
    __syncthreads();
  }
  #pragma unroll
  for (int si = 0; si < 4; si++){
    float s = rsum[si];
    s += __shfl_xor(s, 16);
    s += __shfl_xor(s, 32);
    if (lk == 0){
      int il = wi4 * 64 + si * 16 + lr;
      part[((size_t)b * NN + i0 + il) * 32 + jblk * 2 + wj2] = s;
    }
  }
}

// ---------------- O GEMM v4: 128i x 128c, 2-phase interleave, counted vmcnt(2), rowsum folded ----------------
__global__ __launch_bounds__(512) void k_gemm_o(const ushort* __restrict__ P, const ushort* __restrict__ vv,
                                                const float* __restrict__ part, ushort* __restrict__ ot){
  __shared__ __align__(16) char smem[65536];   // Vs[2][16KB] @0, Ps[2][16KB] @32KB
  int lin = blockIdx.x + 4 * blockIdx.y + 128 * blockIdx.z;    // 0..255
  int tt0 = (lin & 7) * 32 + (lin >> 3);
  int cblk = tt0 & 3;
  int ib   = tt0 >> 2;
  int b = ib >> 5;
  int c0 = cblk * 128, i0 = (ib & 31) * 128;
  int t = threadIdx.x, w = t >> 6, l = t & 63;
  int lr = l & 15, lk = l >> 4;
  int wi2 = w >> 2, wc4 = w & 3;
  const ushort* vb = vv + ((size_t)b * CC + c0) * NN;
  const ushort* pb = P + ((size_t)b * NN + i0) * NN;
  int srow = l >> 3;
  int schunk = (l & 7) ^ srow;

#define STAGE_V(BUF, K0)                                                          \
  {                                                                               \
    ushort* D = (ushort*)(smem + (BUF) * 16384);                                  \
    _Pragma("unroll")                                                             \
    for (int tt = 0; tt < 2; tt++){                                               \
      int g = w * 2 + tt;                                                         \
      const ushort* src = vb + (size_t)(g * 8 + srow) * NN + (K0) + schunk * 8;   \
      GLOAD_LDS16(src, D + g * 512);                                              \
    }                                                                             \
  }
#define STAGE_P(BUF, K0)                                                          \
  {                                                                               \
    ushort* D = (ushort*)(smem + 32768 + (BUF) * 16384);                          \
    _Pragma("unroll")                                                             \
    for (int tt = 0; tt < 2; tt++){                                               \
      int g = w * 2 + tt;                                                         \
      const ushort* src = pb + (size_t)(g * 8 + srow) * NN + (K0) + schunk * 8;   \
      GLOAD_LDS16(src, D + g * 512);                                              \
    }                                                                             \
  }

  f32x4 acc[2][4] = {};   // [sc][si]
  STAGE_V(0, 0)
  STAGE_P(0, 0)
  STAGE_P(1, 64)
  for (int s64 = 0; s64 < 64; s64++){
    const int tau = s64 & 1;
    const ushort* Vs = (const ushort*)(smem + tau * 16384);
    const ushort* Ps = (const ushort*)(smem + 32768 + tau * 16384);
    if (s64 < 63){ asm volatile("s_waitcnt vmcnt(2)" ::: "memory"); }
    else         { asm volatile("s_waitcnt vmcnt(0)" ::: "memory"); }
    __builtin_amdgcn_s_barrier();
    __builtin_amdgcn_sched_barrier(0);
    int xs0 = (lk ^ (lr & 7)) * 8;
    int xs1 = ((4 + lk) ^ (lr & 7)) * 8;
    s16x8 bf[4][2];
    #pragma unroll
    for (int si = 0; si < 4; si++){
      bf[si][0] = *(const s16x8*)&Ps[(wi2 * 64 + si * 16 + lr) * 64 + xs0];
      bf[si][1] = *(const s16x8*)&Ps[(wi2 * 64 + si * 16 + lr) * 64 + xs1];
    }
    // ph0: V kk0 + stage V(s+1)
    {
      s16x8 af0 = *(const s16x8*)&Vs[(wc4 * 32 + lr) * 64 + xs0];
      s16x8 af1 = *(const s16x8*)&Vs[(wc4 * 32 + 16 + lr) * 64 + xs0];
      if (s64 < 63) STAGE_V(tau ^ 1, (s64 + 1) * 64)
      __builtin_amdgcn_s_barrier();
      asm volatile("s_waitcnt lgkmcnt(0)" ::: "memory");
      __builtin_amdgcn_sched_barrier(0);
      __builtin_amdgcn_s_setprio(1);
      #pragma unroll
      for (int si = 0; si < 4; si++){
        acc[0][si] = mfma16(af0, bf[si][0], acc[0][si]);
        acc[1][si] = mfma16(af1, bf[si][0], acc[1][si]);
      }
      __builtin_amdgcn_s_setprio(0);
      __builtin_amdgcn_s_barrier();
    }
    // ph1: V kk1 + stage P(s+2) into freed pbuf tau
    {
      s16x8 af0 = *(const s16x8*)&Vs[(wc4 * 32 + lr) * 64 + xs1];
      s16x8 af1 = *(const s16x8*)&Vs[(wc4 * 32 + 16 + lr) * 64 + xs1];
      if (s64 < 62) STAGE_P(tau, (s64 + 2) * 64)
      __builtin_amdgcn_s_barrier();
      asm volatile("s_waitcnt lgkmcnt(0)" ::: "memory");
      __builtin_amdgcn_sched_barrier(0);
      __builtin_amdgcn_s_setprio(1);
      #pragma unroll
      for (int si = 0; si < 4; si++){
        acc[0][si] = mfma16(af0, bf[si][1], acc[0][si]);
        acc[1][si] = mfma16(af1, bf[si][1], acc[1][si]);
      }
      __builtin_amdgcn_s_setprio(0);
      __builtin_amdgcn_s_barrier();
    }
  }
#undef STAGE_V
#undef STAGE_P
  // folded row-sum: linv for this block's 128 i rows
  ushort* Oe = (ushort*)smem;                 // [128 i][136 c] = 34816 B
  float* linv_lds = (float*)(smem + 34816);   // 512 B
  if (t < 128){
    const float* pp = part + ((size_t)b * NN + i0 + t) * 32;
    float s = 0.f;
    #pragma unroll
    for (int k = 0; k < 32; k++) s += pp[k];
    linv_lds[t] = 1.0f / s;
  }
  __syncthreads();
  #pragma unroll
  for (int si = 0; si < 4; si++){
    int il = wi2 * 64 + si * 16 + lr;
    float li = linv_lds[il];
    #pragma unroll
    for (int sc = 0; sc < 2; sc++){
      int cl = wc4 * 32 + sc * 16 + lk * 4;
      s16x4 pk;
      #pragma unroll
      for (int r = 0; r < 4; r++) pk[r] = f2bfs(acc[sc][si][r] * li);
      *(s16x4*)&Oe[il * 136 + cl] = pk;
    }
  }
  __syncthreads();
  {
    int row = t >> 2, cs = (t & 3) * 32;
    ushort* dst = ot + ((size_t)b * NN + i0 + row) * CC + c0 + cs;
    #pragma unroll
    for (int k = 0; k < 4; k++)
      *(s16x8*)&dst[k * 8] = *(const s16x8*)&Oe[row * 136 + cs + k * 8];
  }
}

// ---------------- proj GEMM v3: 64o x 128n, BK=32, dbuf; XCD-chunked (ob fastest) ----------------
__global__ __launch_bounds__(256, 3) void k_gemm_proj2(const ushort* __restrict__ A, const ushort* __restrict__ Bt,
                                                       const float* __restrict__ bias, float* __restrict__ o32,
                                                       const float* __restrict__ xres){
  __shared__ __align__(16) char smem[34048];
  __shared__ float bl[64];
  // XCD swizzle: same (nb,b) per XCD, ob fastest -> attn-out n-slice L2-resident
  int lin = blockIdx.x + 32 * blockIdx.y + 256 * blockIdx.z;   // 0..511
  int tt0 = (lin & 7) * 64 + (lin >> 3);
  int obk = tt0 & 7;
  int rest = tt0 >> 3;          // 0..63
  int b = rest >> 5;
  int ob = obk * 64, nb = (rest & 31) * 128;
  int t = threadIdx.x, w = t >> 6, l = t & 63;
  int lr = l & 15, lk = l >> 4;
  int wo = (w >> 1) * 32, wn = (w & 1) * 64;
  if (t < 64) bl[t] = bias[ob + t];
  const ushort* Bp = Bt + ((size_t)b * NN + nb) * CC;
  const ushort* Ap = A + (size_t)ob * CC;
  int srow = l >> 2;
  int schunk = (l & 3) ^ ((l >> 2) & 3) ^ ((l >> 4) & 3);
  int xs = (lk ^ (lr & 3) ^ ((lr >> 2) & 3)) * 8;

#define STAGE_P2(BUF, K0)                                                         \
  {                                                                               \
    ushort* As_ = (ushort*)(smem + (BUF) * 12288);                                \
    ushort* Bs_ = As_ + 2048;                                                     \
    _Pragma("unroll")                                                             \
    for (int tt = 0; tt < 3; tt++){                                               \
      int inst = w * 3 + tt;                                                      \
      if (inst < 4){                                                              \
        const ushort* src = Ap + (size_t)(inst * 16 + srow) * CC + (K0) + schunk * 8; \
        GLOAD_LDS16(src, As_ + inst * 512);                                       \
      } else {                                                                    \
        int q = inst - 4;                                                         \
        const ushort* src = Bp + (size_t)(q * 16 + srow) * CC + (K0) + schunk * 8; \
        GLOAD_LDS16(src, Bs_ + q * 512);                                          \
      }                                                                           \
    }                                                                             \
  }

  f32x4 acc[2][4] = {};
  STAGE_P2(0, 0)
  __syncthreads();
  for (int s16 = 0; s16 < 16; s16++){
    if (s16 < 15) STAGE_P2((s16 + 1) & 1, (s16 + 1) * 32)
    const ushort* As = (const ushort*)(smem + (s16 & 1) * 12288);
    const ushort* Bs = As + 2048;
    s16x8 a0 = *(const s16x8*)&As[(wo + lr) * 32 + xs];
    s16x8 a1 = *(const s16x8*)&As[(wo + 16 + lr) * 32 + xs];
    #pragma unroll
    for (int sn = 0; sn < 4; sn++){
      s16x8 bf = *(const s16x8*)&Bs[(wn + sn * 16 + lr) * 32 + xs];
      acc[0][sn] = mfma16(a0, bf, acc[0][sn]);
      acc[1][sn] = mfma16(a1, bf, acc[1][sn]);
    }
    __syncthreads();
  }
#undef STAGE_P2
  float* trf = (float*)smem;   // [64][133]
  #pragma unroll
  for (int so = 0; so < 2; so++)
    #pragma unroll
    for (int sn = 0; sn < 4; sn++){
      int o0 = wo + so * 16 + lk * 4;
      int ncl = wn + sn * 16 + lr;
      #pragma unroll
      for (int r = 0; r < 4; r++) trf[(o0 + r) * 133 + ncl] = acc[so][sn][r] + bl[o0 + r];
    }
  __syncthreads();
  {
    int row = t >> 2, cs = (t & 3) * 32;
    size_t base = ((size_t)b * CC + ob + row) * NN + nb + cs;
    #pragma unroll
    for (int q = 0; q < 8; q++){
      float4 xv = *reinterpret_cast<const float4*>(&xres[base + q * 4]);
      float4 ov;
      ov.x = xv.x + trf[row * 133 + cs + q * 4 + 0];
      ov.y = xv.y + trf[row * 133 + cs + q * 4 + 1];
      ov.z = xv.z + trf[row * 133 + cs + q * 4 + 2];
      ov.w = xv.w + trf[row * 133 + cs + q * 4 + 3];
      *reinterpret_cast<float4*>(&o32[base + q * 4]) = ov;
    }
  }
}

extern "C" void kernel_launch(void* const* d_in, const int* in_sizes, int n_in,
                              void* d_out, int out_size, void* d_ws, size_t ws_size,
                              hipStream_t stream){
  const float* x   = (const float*)d_in[0];
  const float* gsc = (const float*)d_in[1];
  const float* gbi = (const float*)d_in[2];
  const float* wq  = (const float*)d_in[3];
  const float* bq  = (const float*)d_in[4];
  const float* wk  = (const float*)d_in[5];
  const float* bk  = (const float*)d_in[6];
  const float* wv  = (const float*)d_in[7];
  const float* bv  = (const float*)d_in[8];
  const float* wp  = (const float*)d_in[9];
  const float* bp  = (const float*)d_in[10];
  char* ws = (char*)d_ws;
  const size_t MB = 1024 * 1024;
  // workspace map:
  ushort* wbf  = (ushort*)ws;                    // [0,2MB): bf16 weights
  ushort* qtb  = (ushort*)(ws + 2 * MB);         // [2,10): q^T; DEAD after gemm_s -> reused as attn-out ot
  ushort* ktb  = (ushort*)(ws + 10 * MB);        // [10,18): k^T
  ushort* vvb  = (ushort*)(ws + 18 * MB);        // [18,26): v [b][c][n]
  ushort* hfb  = (ushort*)(ws + 26 * MB);        // [26,34): hf^T; DEAD after qkv2 -> part lives here
  ushort* Pbuf = (ushort*)(ws + 34 * MB);        // [34,98): P = exp2(S) bf16
  float* pstat = (float*)(ws + 98 * MB);         // 2 KB GN partial stats
  float* part  = (float*)(ws + 26 * MB);         // 1MB row-sum partials (dead-hf window)
  ushort* otb  = qtb;                            // attn-out in dead q^T region

  const float rs = 0.044194173824159216f * 1.4426950408889634f;

  k_prep<<<512, 256, 0, stream>>>(wq, wk, wv, wp, wbf, x, pstat);
  k_gn_apply<<<dim3(128, 2, 1), 256, 0, stream>>>(x, gsc, gbi, pstat, hfb);
  k_gemm_qkv2<<<dim3(32, 8, 2), 256, 0, stream>>>(wbf, hfb, bq, bk, bv, qtb, ktb, vvb, rs);
  k_gemm_s<<<dim3(16, 16, 2), 512, 131072, stream>>>(qtb, ktb, Pbuf, part);
  k_gemm_o<<<dim3(4, 32, 2), 512, 0, stream>>>(Pbuf, vvb, part, otb);
  k_gemm_proj2<<<dim3(32, 8, 2), 256, 0, stream>>>(wbf + 3 * CC * CC, otb, bp, (float*)d_out, x);
}

// Round 21
// 166.116 us; speedup vs baseline: 1.0056x; 1.0056x over previous
//
#include <hip/hip_runtime.h>
#include <hip/hip_bf16.h>

#define BB 2
#define CC 512
#define GG 32
#define NN 4096
#define EPSV 1e-6f

typedef __attribute__((ext_vector_type(4))) float f32x4;
typedef __attribute__((ext_vector_type(8))) short s16x8;
typedef __attribute__((ext_vector_type(4))) short s16x4;

__device__ __forceinline__ ushort f2bf(float f){
  union { float f; unsigned u; } v; v.f = f;
  unsigned r = v.u + 0x7fffu + ((v.u >> 16) & 1u);
  return (ushort)(r >> 16);
}
__device__ __forceinline__ short f2bfs(float f){ return (short)f2bf(f); }
__device__ __forceinline__ float b2f(ushort u){
  union { unsigned u; float f; } v; v.u = ((unsigned)u) << 16; return v.f;
}

__device__ __forceinline__ f32x4 mfma16(s16x8 a, s16x8 b, f32x4 c){
  return __builtin_amdgcn_mfma_f32_16x16x32_bf16(a, b, c, 0, 0, 0);
}

#define GLOAD_LDS16(g, l) __builtin_amdgcn_global_load_lds( \
    (const __attribute__((address_space(1))) void*)(g),     \
    (__attribute__((address_space(3))) void*)(l), 16, 0, 0)

// ---------------- prep: weight fp32->bf16 (blocks 256..511) + GN stats stage1 (blocks 0..255) ----------------
__global__ __launch_bounds__(256) void k_prep(const float* __restrict__ wq, const float* __restrict__ wk,
                                              const float* __restrict__ wv, const float* __restrict__ wp,
                                              ushort* __restrict__ wbf,
                                              const float* __restrict__ x, float* __restrict__ pstat){
  if (blockIdx.x >= 256){
    int idx = (blockIdx.x - 256) * 256 + threadIdx.x;
    const float* srcs[4] = {wq, wk, wv, wp};
    #pragma unroll
    for (int m = 0; m < 4; m++){
      float4 v = reinterpret_cast<const float4*>(srcs[m])[idx];
      ushort4 o; o.x = f2bf(v.x); o.y = f2bf(v.y); o.z = f2bf(v.z); o.w = f2bf(v.w);
      reinterpret_cast<ushort4*>(wbf + (size_t)m * CC * CC)[idx] = o;
    }
    return;
  }
  int blk = blockIdx.x;   // 0..255, chunk of 16384 floats
  const float* p = x + (size_t)blk * 16384;
  float s = 0.f, ss = 0.f;
  for (int i = threadIdx.x; i < 4096; i += 256){
    float4 v = reinterpret_cast<const float4*>(p)[i];
    s  += v.x + v.y + v.z + v.w;
    ss += v.x*v.x + v.y*v.y + v.z*v.z + v.w*v.w;
  }
  #pragma unroll
  for (int off = 32; off; off >>= 1){ s += __shfl_down(s, off); ss += __shfl_down(ss, off); }
  __shared__ float rs_[4], rss_[4];
  int w = threadIdx.x >> 6, lane = threadIdx.x & 63;
  if (lane == 0){ rs_[w] = s; rss_[w] = ss; }
  __syncthreads();
  if (threadIdx.x == 0){
    pstat[blk * 2 + 0] = rs_[0] + rs_[1] + rs_[2] + rs_[3];
    pstat[blk * 2 + 1] = rss_[0] + rss_[1] + rss_[2] + rss_[3];
  }
}

// ---------------- GN apply + transpose, stats stage2 folded ----------------
__global__ __launch_bounds__(256) void k_gn_apply(const float* __restrict__ x, const float* __restrict__ gsc,
                                                  const float* __restrict__ gbi, const float* __restrict__ pstat,
                                                  ushort* __restrict__ hf){
  __shared__ ushort tr[32][520];
  __shared__ float stl[64];   // 32 groups x {mean, rstd} for this b
  int b = blockIdx.y;
  int nb = blockIdx.x * 32;
  int t = threadIdx.x;
  if (t < 32){
    float s = 0.f, ss = 0.f;
    #pragma unroll
    for (int k = 0; k < 4; k++){
      s  += pstat[(b * 128 + t * 4 + k) * 2 + 0];
      ss += pstat[(b * 128 + t * 4 + k) * 2 + 1];
    }
    float inv = 1.0f / (16.0f * NN);
    float mean = s * inv;
    float var = ss * inv - mean * mean;
    stl[t * 2 + 0] = mean;
    stl[t * 2 + 1] = rsqrtf(var + EPSV);
  }
  __syncthreads();
  int n = t & 31, cr = t >> 5;
  const float* xb = x + (size_t)b * CC * NN;
  for (int c0 = 0; c0 < CC; c0 += 8){
    int c = c0 + cr;
    float mean = stl[(c >> 4) * 2 + 0];
    float rstd = stl[(c >> 4) * 2 + 1];
    float v = xb[(size_t)c * NN + nb + n];
    tr[n][c] = f2bf((v - mean) * rstd * gsc[c] + gbi[c]);
  }
  __syncthreads();
  ushort* out = hf + ((size_t)b * NN + nb) * CC;
  int c8 = (t & 63) * 8;
  int nrow0 = t >> 6;
  #pragma unroll
  for (int i = 0; i < 8; i++){
    int nr = nrow0 + i * 4;
    *reinterpret_cast<s16x8*>(&out[(size_t)nr * CC + c8]) =
      *reinterpret_cast<const s16x8*>(&tr[nr][c8]);
  }
}

// ---------------- fused QKV GEMM v2: 64o x 128n tile, BK=32, dbuf gload_lds ----------------
__global__ __launch_bounds__(256, 3) void k_gemm_qkv2(const ushort* __restrict__ W, const ushort* __restrict__ Bt,
                                                      const float* __restrict__ bq, const float* __restrict__ bk,
                                                      const float* __restrict__ bv,
                                                      ushort* __restrict__ qo, ushort* __restrict__ ko,
                                                      ushort* __restrict__ vo, float rs){
  __shared__ __align__(16) char smem[40960];
  __shared__ float bl[3][64];
  int b = blockIdx.z, ob = blockIdx.y * 64, nb = blockIdx.x * 128;
  int t = threadIdx.x, w = t >> 6, l = t & 63;
  int lr = l & 15, lk = l >> 4;
  int wo = (w >> 1) * 32, wn = (w & 1) * 64;
  if (t < 64){ bl[0][t] = bq[ob + t]; bl[1][t] = bk[ob + t]; bl[2][t] = bv[ob + t]; }
  const ushort* Bp = Bt + ((size_t)b * NN + nb) * CC;
  const ushort* Wp = W + (size_t)ob * CC;
  int srow = l >> 2;
  int schunk = (l & 3) ^ ((l >> 2) & 3) ^ ((l >> 4) & 3);
  int xs = (lk ^ (lr & 3) ^ ((lr >> 2) & 3)) * 8;

#define STAGE_QKV(BUF, K0)                                                               \
  {                                                                                      \
    ushort* As_ = (ushort*)(smem + (BUF) * 20480);                                       \
    ushort* Bs_ = As_ + 6144;                                                            \
    _Pragma("unroll")                                                                    \
    for (int tt = 0; tt < 5; tt++){                                                      \
      int inst = w * 5 + tt;                                                             \
      if (inst < 12){                                                                    \
        int m = inst >> 2, sub = inst & 3;                                               \
        const ushort* src = Wp + (size_t)m * CC * CC + (size_t)(sub * 16 + srow) * CC + (K0) + schunk * 8; \
        GLOAD_LDS16(src, As_ + m * 2048 + sub * 512);                                    \
      } else {                                                                           \
        int q = inst - 12;                                                               \
        const ushort* src = Bp + (size_t)(q * 16 + srow) * CC + (K0) + schunk * 8;       \
        GLOAD_LDS16(src, Bs_ + q * 512);                                                 \
      }                                                                                  \
    }                                                                                    \
  }

  f32x4 acc[3][2][4] = {};
  STAGE_QKV(0, 0)
  __syncthreads();
  for (int s16 = 0; s16 < 16; s16++){
    if (s16 < 15) STAGE_QKV((s16 + 1) & 1, (s16 + 1) * 32)
    const ushort* As = (const ushort*)(smem + (s16 & 1) * 20480);
    const ushort* Bs = As + 6144;
    s16x8 bf[4];
    #pragma unroll
    for (int sn = 0; sn < 4; sn++)
      bf[sn] = *(const s16x8*)&Bs[(wn + sn * 16 + lr) * 32 + xs];
    #pragma unroll
    for (int m = 0; m < 3; m++){
      s16x8 a0 = *(const s16x8*)&As[m * 2048 + (wo + lr) * 32 + xs];
      s16x8 a1 = *(const s16x8*)&As[m * 2048 + (wo + 16 + lr) * 32 + xs];
      #pragma unroll
      for (int sn = 0; sn < 4; sn++){
        acc[m][0][sn] = mfma16(a0, bf[sn], acc[m][0][sn]);
        acc[m][1][sn] = mfma16(a1, bf[sn], acc[m][1][sn]);
      }
    }
    __syncthreads();
  }
#undef STAGE_QKV
  #pragma unroll
  for (int m = 0; m < 2; m++){
    ushort* dst = (m == 0) ? qo : ko;
    float scl = (m == 0) ? rs : 1.0f;
    #pragma unroll
    for (int so = 0; so < 2; so++)
      #pragma unroll
      for (int sn = 0; sn < 4; sn++){
        int o0 = wo + so * 16 + lk * 4;
        int n  = nb + wn + sn * 16 + lr;
        s16x4 pv;
        #pragma unroll
        for (int r = 0; r < 4; r++) pv[r] = f2bfs((acc[m][so][sn][r] + bl[m][o0 + r]) * scl);
        *reinterpret_cast<s16x4*>(&dst[((size_t)b * NN + n) * CC + ob + o0]) = pv;
      }
  }
  ushort* Ve = (ushort*)smem;   // [64][136]
  #pragma unroll
  for (int so = 0; so < 2; so++)
    #pragma unroll
    for (int sn = 0; sn < 4; sn++){
      int o0 = wo + so * 16 + lk * 4;
      int ncl = wn + sn * 16 + lr;
      #pragma unroll
      for (int r = 0; r < 4; r++) Ve[(o0 + r) * 136 + ncl] = f2bf(acc[2][so][sn][r] + bl[2][o0 + r]);
    }
  __syncthreads();
  {
    int row = t >> 2, cs = (t & 3) * 32;
    ushort* dst = &vo[((size_t)b * CC + ob + row) * NN + nb + cs];
    #pragma unroll
    for (int k = 0; k < 4; k++)
      *(s16x8*)&dst[k * 8] = *(const s16x8*)&Ve[row * 136 + cs + k * 8];
  }
}

// ---------------- S GEMM v6: 256x256, BK=64, 4-phase interleaved schedule ----------------
__global__ __launch_bounds__(512, 2) void k_gemm_s(const ushort* __restrict__ qt, const ushort* __restrict__ kt,
                                                   ushort* __restrict__ P, float* __restrict__ part){
  extern __shared__ __align__(16) char smem[];   // Kbuf[2][32KB] @0, Qbuf[2][32KB] @64KB
  int lin = blockIdx.x + 16 * blockIdx.y + 256 * blockIdx.z;   // 0..511
  int tt0 = (lin & 7) * 64 + (lin >> 3);
  int jblk = tt0 & 15;
  int pair = tt0 >> 4;
  int b = pair >> 4;
  int j0 = jblk * 256, i0 = (pair & 15) * 256;
  int t = threadIdx.x, w = t >> 6, l = t & 63;
  int lr = l & 15, lk = l >> 4;
  int wj2 = w >> 2, wi4 = w & 3;
  const ushort* kb = kt + ((size_t)b * NN + j0) * CC;
  const ushort* qb = qt + ((size_t)b * NN + i0) * CC;
  int srow = l >> 3;
  int schunk = (l & 7) ^ srow;

#define STAGE_KH(BUF, K0, H)                                                      \
  {                                                                               \
    ushort* D = (ushort*)(smem + (BUF) * 32768);                                  \
    _Pragma("unroll")                                                             \
    for (int tt = 0; tt < 2; tt++){                                               \
      int g = (H) * 16 + w * 2 + tt;                                              \
      const ushort* src = kb + (size_t)(g * 8 + srow) * CC + (K0) + schunk * 8;   \
      GLOAD_LDS16(src, D + g * 512);                                              \
    }                                                                             \
  }
#define STAGE_QH(BUF, K0, H)                                                      \
  {                                                                               \
    ushort* D = (ushort*)(smem + 65536 + (BUF) * 32768);                          \
    _Pragma("unroll")                                                             \
    for (int tt = 0; tt < 2; tt++){                                               \
      int g = (H) * 16 + w * 2 + tt;                                              \
      const ushort* src = qb + (size_t)(g * 8 + srow) * CC + (K0) + schunk * 8;   \
      GLOAD_LDS16(src, D + g * 512);                                              \
    }                                                                             \
  }
#define PHASE(SJ, STAGE_CODE)                                                     \
  {                                                                               \
    s16x8 a00 = *(const s16x8*)&Ks[(wj2 * 128 + (SJ) * 16 + lr) * 64 + xs0];      \
    s16x8 a01 = *(const s16x8*)&Ks[(wj2 * 128 + (SJ) * 16 + lr) * 64 + xs1];      \
    s16x8 a10 = *(const s16x8*)&Ks[(wj2 * 128 + ((SJ) + 1) * 16 + lr) * 64 + xs0];\
    s16x8 a11 = *(const s16x8*)&Ks[(wj2 * 128 + ((SJ) + 1) * 16 + lr) * 64 + xs1];\
    STAGE_CODE                                                                    \
    __builtin_amdgcn_s_barrier();                                                 \
    asm volatile("s_waitcnt lgkmcnt(0)" ::: "memory");                            \
    __builtin_amdgcn_sched_barrier(0);                                            \
    __builtin_amdgcn_s_setprio(1);                                                \
    _Pragma("unroll")                                                             \
    for (int si = 0; si < 4; si++){                                               \
      acc[SJ][si]       = mfma16(a00, bq[si][0], acc[SJ][si]);                    \
      acc[SJ][si]       = mfma16(a01, bq[si][1], acc[SJ][si]);                    \
      acc[(SJ) + 1][si] = mfma16(a10, bq[si][0], acc[(SJ) + 1][si]);              \
      acc[(SJ) + 1][si] = mfma16(a11, bq[si][1], acc[(SJ) + 1][si]);              \
    }                                                                             \
    __builtin_amdgcn_s_setprio(0);                                                \
    __builtin_amdgcn_s_barrier();                                                 \
  }

  f32x4 acc[8][4] = {};
  STAGE_KH(0, 0, 0)
  STAGE_KH(0, 0, 1)
  STAGE_QH(0, 0, 0)
  STAGE_QH(0, 0, 1)
  STAGE_QH(1, 64, 0)
  STAGE_QH(1, 64, 1)
  #pragma unroll
  for (int s8 = 0; s8 < 8; s8++){
    const int tau = s8 & 1;
    const ushort* Ks = (const ushort*)(smem + tau * 32768);
    const ushort* Qs = (const ushort*)(smem + 65536 + tau * 32768);
    if (s8 < 7){ asm volatile("s_waitcnt vmcnt(4)" ::: "memory"); }
    else       { asm volatile("s_waitcnt vmcnt(0)" ::: "memory"); }
    __builtin_amdgcn_s_barrier();
    __builtin_amdgcn_sched_barrier(0);
    int xs0 = (lk ^ (lr & 7)) * 8;
    int xs1 = ((4 + lk) ^ (lr & 7)) * 8;
    s16x8 bq[4][2];
    #pragma unroll
    for (int si = 0; si < 4; si++){
      bq[si][0] = *(const s16x8*)&Qs[(wi4 * 64 + si * 16 + lr) * 64 + xs0];
      bq[si][1] = *(const s16x8*)&Qs[(wi4 * 64 + si * 16 + lr) * 64 + xs1];
    }
    PHASE(0, if (s8 < 7) STAGE_KH(tau ^ 1, (s8 + 1) * 64, 0))
    PHASE(2, if (s8 < 7) STAGE_KH(tau ^ 1, (s8 + 1) * 64, 1))
    PHASE(4, if (s8 < 6) STAGE_QH(tau, (s8 + 2) * 64, 0))
    PHASE(6, if (s8 < 6) STAGE_QH(tau, (s8 + 2) * 64, 1))
  }
#undef PHASE
#undef STAGE_KH
#undef STAGE_QH
  ushort* Pe = (ushort*)smem;   // [128 i][264 j] per pass
  float rsum[4] = {0.f, 0.f, 0.f, 0.f};
  #pragma unroll
  for (int pass = 0; pass < 2; pass++){
    if ((wi4 >> 1) == pass){
      #pragma unroll
      for (int sj = 0; sj < 8; sj++)
        #pragma unroll
        for (int si = 0; si < 4; si++){
          int il = (wi4 & 1) * 64 + si * 16 + lr;
          int jl = wj2 * 128 + sj * 16 + lk * 4;
          s16x4 pk;
          #pragma unroll
          for (int r = 0; r < 4; r++){
            float e = __builtin_amdgcn_exp2f(acc[sj][si][r]);
            pk[r] = f2bfs(e);
            rsum[si] += e;
          }
          *(s16x4*)&Pe[il * 264 + jl] = pk;
        }
    }
    __syncthreads();
    {
      int row = t >> 2, cs = (t & 3) * 64;
      ushort* dst = P + ((size_t)b * NN + i0 + pass * 128 + row) * NN + j0 + cs;
      #pragma unroll
      for (int k = 0; k < 8; k++)
        *(s16x8*)&dst[k * 8] = *(const s16x8*)&Pe[row * 264 + cs + k * 8];
    }
    __syncthreads();
  }
  #pragma unroll
  for (int si = 0; si < 4; si++){
    float s = rsum[si];
    s += __shfl_xor(s, 16);
    s += __shfl_xor(s, 32);
    if (lk == 0){
      int il = wi4 * 64 + si * 16 + lr;
      part[((size_t)b * NN + i0 + il) * 32 + jblk * 2 + wj2] = s;
    }
  }
}

// ---------------- O GEMM v4: 128i x 128c, 2-phase interleave, counted vmcnt(2), rowsum folded ----------------
__global__ __launch_bounds__(512) void k_gemm_o(const ushort* __restrict__ P, const ushort* __restrict__ vv,
                                                const float* __restrict__ part, ushort* __restrict__ ot){
  __shared__ __align__(16) char smem[65536];   // Vs[2][16KB] @0, Ps[2][16KB] @32KB
  int lin = blockIdx.x + 4 * blockIdx.y + 128 * blockIdx.z;    // 0..255
  int tt0 = (lin & 7) * 32 + (lin >> 3);
  int cblk = tt0 & 3;
  int ib   = tt0 >> 2;
  int b = ib >> 5;
  int c0 = cblk * 128, i0 = (ib & 31) * 128;
  int t = threadIdx.x, w = t >> 6, l = t & 63;
  int lr = l & 15, lk = l >> 4;
  int wi2 = w >> 2, wc4 = w & 3;
  const ushort* vb = vv + ((size_t)b * CC + c0) * NN;
  const ushort* pb = P + ((size_t)b * NN + i0) * NN;
  int srow = l >> 3;
  int schunk = (l & 7) ^ srow;

#define STAGE_V(BUF, K0)                                                          \
  {                                                                               \
    ushort* D = (ushort*)(smem + (BUF) * 16384);                                  \
    _Pragma("unroll")                                                             \
    for (int tt = 0; tt < 2; tt++){                                               \
      int g = w * 2 + tt;                                                         \
      const ushort* src = vb + (size_t)(g * 8 + srow) * NN + (K0) + schunk * 8;   \
      GLOAD_LDS16(src, D + g * 512);                                              \
    }                                                                             \
  }
#define STAGE_P(BUF, K0)                                                          \
  {                                                                               \
    ushort* D = (ushort*)(smem + 32768 + (BUF) * 16384);                          \
    _Pragma("unroll")                                                             \
    for (int tt = 0; tt < 2; tt++){                                               \
      int g = w * 2 + tt;                                                         \
      const ushort* src = pb + (size_t)(g * 8 + srow) * NN + (K0) + schunk * 8;   \
      GLOAD_LDS16(src, D + g * 512);                                              \
    }                                                                             \
  }

  f32x4 acc[2][4] = {};   // [sc][si]
  STAGE_V(0, 0)
  STAGE_P(0, 0)
  STAGE_P(1, 64)
  for (int s64 = 0; s64 < 64; s64++){
    const int tau = s64 & 1;
    const ushort* Vs = (const ushort*)(smem + tau * 16384);
    const ushort* Ps = (const ushort*)(smem + 32768 + tau * 16384);
    if (s64 < 63){ asm volatile("s_waitcnt vmcnt(2)" ::: "memory"); }
    else         { asm volatile("s_waitcnt vmcnt(0)" ::: "memory"); }
    __builtin_amdgcn_s_barrier();
    __builtin_amdgcn_sched_barrier(0);
    int xs0 = (lk ^ (lr & 7)) * 8;
    int xs1 = ((4 + lk) ^ (lr & 7)) * 8;
    s16x8 bf[4][2];
    #pragma unroll
    for (int si = 0; si < 4; si++){
      bf[si][0] = *(const s16x8*)&Ps[(wi2 * 64 + si * 16 + lr) * 64 + xs0];
      bf[si][1] = *(const s16x8*)&Ps[(wi2 * 64 + si * 16 + lr) * 64 + xs1];
    }
    // ph0: V kk0 + stage V(s+1)
    {
      s16x8 af0 = *(const s16x8*)&Vs[(wc4 * 32 + lr) * 64 + xs0];
      s16x8 af1 = *(const s16x8*)&Vs[(wc4 * 32 + 16 + lr) * 64 + xs0];
      if (s64 < 63) STAGE_V(tau ^ 1, (s64 + 1) * 64)
      __builtin_amdgcn_s_barrier();
      asm volatile("s_waitcnt lgkmcnt(0)" ::: "memory");
      __builtin_amdgcn_sched_barrier(0);
      __builtin_amdgcn_s_setprio(1);
      #pragma unroll
      for (int si = 0; si < 4; si++){
        acc[0][si] = mfma16(af0, bf[si][0], acc[0][si]);
        acc[1][si] = mfma16(af1, bf[si][0], acc[1][si]);
      }
      __builtin_amdgcn_s_setprio(0);
      __builtin_amdgcn_s_barrier();
    }
    // ph1: V kk1 + stage P(s+2) into freed pbuf tau
    {
      s16x8 af0 = *(const s16x8*)&Vs[(wc4 * 32 + lr) * 64 + xs1];
      s16x8 af1 = *(const s16x8*)&Vs[(wc4 * 32 + 16 + lr) * 64 + xs1];
      if (s64 < 62) STAGE_P(tau, (s64 + 2) * 64)
      __builtin_amdgcn_s_barrier();
      asm volatile("s_waitcnt lgkmcnt(0)" ::: "memory");
      __builtin_amdgcn_sched_barrier(0);
      __builtin_amdgcn_s_setprio(1);
      #pragma unroll
      for (int si = 0; si < 4; si++){
        acc[0][si] = mfma16(af0, bf[si][1], acc[0][si]);
        acc[1][si] = mfma16(af1, bf[si][1], acc[1][si]);
      }
      __builtin_amdgcn_s_setprio(0);
      __builtin_amdgcn_s_barrier();
    }
  }
#undef STAGE_V
#undef STAGE_P
  // folded row-sum: linv for this block's 128 i rows
  ushort* Oe = (ushort*)smem;                 // [128 i][136 c] = 34816 B
  float* linv_lds = (float*)(smem + 34816);   // 512 B
  if (t < 128){
    const float* pp = part + ((size_t)b * NN + i0 + t) * 32;
    float s = 0.f;
    #pragma unroll
    for (int k = 0; k < 32; k++) s += pp[k];
    linv_lds[t] = 1.0f / s;
  }
  __syncthreads();
  #pragma unroll
  for (int si = 0; si < 4; si++){
    int il = wi2 * 64 + si * 16 + lr;
    float li = linv_lds[il];
    #pragma unroll
    for (int sc = 0; sc < 2; sc++){
      int cl = wc4 * 32 + sc * 16 + lk * 4;
      s16x4 pk;
      #pragma unroll
      for (int r = 0; r < 4; r++) pk[r] = f2bfs(acc[sc][si][r] * li);
      *(s16x4*)&Oe[il * 136 + cl] = pk;
    }
  }
  __syncthreads();
  {
    int row = t >> 2, cs = (t & 3) * 32;
    ushort* dst = ot + ((size_t)b * NN + i0 + row) * CC + c0 + cs;
    #pragma unroll
    for (int k = 0; k < 4; k++)
      *(s16x8*)&dst[k * 8] = *(const s16x8*)&Oe[row * 136 + cs + k * 8];
  }
}

// ---------------- proj GEMM v2: 64o x 128n, BK=32, dbuf gload_lds; fp32 out + residual ----------------
__global__ __launch_bounds__(256, 3) void k_gemm_proj2(const ushort* __restrict__ A, const ushort* __restrict__ Bt,
                                                       const float* __restrict__ bias, float* __restrict__ o32,
                                                       const float* __restrict__ xres){
  __shared__ __align__(16) char smem[34048];
  __shared__ float bl[64];
  int b = blockIdx.z, ob = blockIdx.y * 64, nb = blockIdx.x * 128;
  int t = threadIdx.x, w = t >> 6, l = t & 63;
  int lr = l & 15, lk = l >> 4;
  int wo = (w >> 1) * 32, wn = (w & 1) * 64;
  if (t < 64) bl[t] = bias[ob + t];
  const ushort* Bp = Bt + ((size_t)b * NN + nb) * CC;
  const ushort* Ap = A + (size_t)ob * CC;
  int srow = l >> 2;
  int schunk = (l & 3) ^ ((l >> 2) & 3) ^ ((l >> 4) & 3);
  int xs = (lk ^ (lr & 3) ^ ((lr >> 2) & 3)) * 8;

#define STAGE_P2(BUF, K0)                                                         \
  {                                                                               \
    ushort* As_ = (ushort*)(smem + (BUF) * 12288);                                \
    ushort* Bs_ = As_ + 2048;                                                     \
    _Pragma("unroll")                                                             \
    for (int tt = 0; tt < 3; tt++){                                               \
      int inst = w * 3 + tt;                                                      \
      if (inst < 4){                                                              \
        const ushort* src = Ap + (size_t)(inst * 16 + srow) * CC + (K0) + schunk * 8; \
        GLOAD_LDS16(src, As_ + inst * 512);                                       \
      } else {                                                                    \
        int q = inst - 4;                                                         \
        const ushort* src = Bp + (size_t)(q * 16 + srow) * CC + (K0) + schunk * 8; \
        GLOAD_LDS16(src, Bs_ + q * 512);                                          \
      }                                                                           \
    }                                                                             \
  }

  f32x4 acc[2][4] = {};
  STAGE_P2(0, 0)
  __syncthreads();
  for (int s16 = 0; s16 < 16; s16++){
    if (s16 < 15) STAGE_P2((s16 + 1) & 1, (s16 + 1) * 32)
    const ushort* As = (const ushort*)(smem + (s16 & 1) * 12288);
    const ushort* Bs = As + 2048;
    s16x8 a0 = *(const s16x8*)&As[(wo + lr) * 32 + xs];
    s16x8 a1 = *(const s16x8*)&As[(wo + 16 + lr) * 32 + xs];
    #pragma unroll
    for (int sn = 0; sn < 4; sn++){
      s16x8 bf = *(const s16x8*)&Bs[(wn + sn * 16 + lr) * 32 + xs];
      acc[0][sn] = mfma16(a0, bf, acc[0][sn]);
      acc[1][sn] = mfma16(a1, bf, acc[1][sn]);
    }
    __syncthreads();
  }
#undef STAGE_P2
  float* trf = (float*)smem;   // [64][133]
  #pragma unroll
  for (int so = 0; so < 2; so++)
    #pragma unroll
    for (int sn = 0; sn < 4; sn++){
      int o0 = wo + so * 16 + lk * 4;
      int ncl = wn + sn * 16 + lr;
      #pragma unroll
      for (int r = 0; r < 4; r++) trf[(o0 + r) * 133 + ncl] = acc[so][sn][r] + bl[o0 + r];
    }
  __syncthreads();
  {
    int row = t >> 2, cs = (t & 3) * 32;
    size_t base = ((size_t)b * CC + ob + row) * NN + nb + cs;
    #pragma unroll
    for (int q = 0; q < 8; q++){
      float4 xv = *reinterpret_cast<const float4*>(&xres[base + q * 4]);
      float4 ov;
      ov.x = xv.x + trf[row * 133 + cs + q * 4 + 0];
      ov.y = xv.y + trf[row * 133 + cs + q * 4 + 1];
      ov.z = xv.z + trf[row * 133 + cs + q * 4 + 2];
      ov.w = xv.w + trf[row * 133 + cs + q * 4 + 3];
      *reinterpret_cast<float4*>(&o32[base + q * 4]) = ov;
    }
  }
}

extern "C" void kernel_launch(void* const* d_in, const int* in_sizes, int n_in,
                              void* d_out, int out_size, void* d_ws, size_t ws_size,
                              hipStream_t stream){
  const float* x   = (const float*)d_in[0];
  const float* gsc = (const float*)d_in[1];
  const float* gbi = (const float*)d_in[2];
  const float* wq  = (const float*)d_in[3];
  const float* bq  = (const float*)d_in[4];
  const float* wk  = (const float*)d_in[5];
  const float* bk  = (const float*)d_in[6];
  const float* wv  = (const float*)d_in[7];
  const float* bv  = (const float*)d_in[8];
  const float* wp  = (const float*)d_in[9];
  const float* bp  = (const float*)d_in[10];
  char* ws = (char*)d_ws;
  const size_t MB = 1024 * 1024;
  // workspace map:
  ushort* wbf  = (ushort*)ws;                    // [0,2MB): bf16 weights
  ushort* qtb  = (ushort*)(ws + 2 * MB);         // [2,10): q^T; DEAD after gemm_s -> reused as attn-out ot
  ushort* ktb  = (ushort*)(ws + 10 * MB);        // [10,18): k^T
  ushort* vvb  = (ushort*)(ws + 18 * MB);        // [18,26): v [b][c][n]
  ushort* hfb  = (ushort*)(ws + 26 * MB);        // [26,34): hf^T; DEAD after qkv2 -> part lives here
  ushort* Pbuf = (ushort*)(ws + 34 * MB);        // [34,98): P = exp2(S) bf16
  float* pstat = (float*)(ws + 98 * MB);         // 2 KB GN partial stats
  float* part  = (float*)(ws + 26 * MB);         // 1MB row-sum partials (dead-hf window)
  ushort* otb  = qtb;                            // attn-out in dead q^T region

  const float rs = 0.044194173824159216f * 1.4426950408889634f;

  k_prep<<<512, 256, 0, stream>>>(wq, wk, wv, wp, wbf, x, pstat);
  k_gn_apply<<<dim3(128, 2, 1), 256, 0, stream>>>(x, gsc, gbi, pstat, hfb);
  k_gemm_qkv2<<<dim3(32, 8, 2), 256, 0, stream>>>(wbf, hfb, bq, bk, bv, qtb, ktb, vvb, rs);
  k_gemm_s<<<dim3(16, 16, 2), 512, 131072, stream>>>(qtb, ktb, Pbuf, part);
  k_gemm_o<<<dim3(4, 32, 2), 512, 0, stream>>>(Pbuf, vvb, part, otb);
  k_gemm_proj2<<<dim3(32, 8, 2), 256, 0, stream>>>(wbf + 3 * CC * CC, otb, bp, (float*)d_out, x);
}

// Round 22
// 166.092 us; speedup vs baseline: 1.0058x; 1.0001x over previous
//
#include <hip/hip_runtime.h>
#include <hip/hip_bf16.h>

#define BB 2
#define CC 512
#define GG 32
#define NN 4096
#define EPSV 1e-6f

typedef __attribute__((ext_vector_type(4))) float f32x4;
typedef __attribute__((ext_vector_type(8))) short s16x8;
typedef __attribute__((ext_vector_type(4))) short s16x4;

__device__ __forceinline__ ushort f2bf(float f){
  union { float f; unsigned u; } v; v.f = f;
  unsigned r = v.u + 0x7fffu + ((v.u >> 16) & 1u);
  return (ushort)(r >> 16);
}
__device__ __forceinline__ short f2bfs(float f){ return (short)f2bf(f); }
__device__ __forceinline__ float b2f(ushort u){
  union { unsigned u; float f; } v; v.u = ((unsigned)u) << 16; return v.f;
}

__device__ __forceinline__ f32x4 mfma16(s16x8 a, s16x8 b, f32x4 c){
  return __builtin_amdgcn_mfma_f32_16x16x32_bf16(a, b, c, 0, 0, 0);
}

#define GLOAD_LDS16(g, l) __builtin_amdgcn_global_load_lds( \
    (const __attribute__((address_space(1))) void*)(g),     \
    (__attribute__((address_space(3))) void*)(l), 16, 0, 0)

// ---------------- prep: weight fp32->bf16 (blocks 256..511) + GN stats stage1 (blocks 0..255) ----------------
__global__ __launch_bounds__(256) void k_prep(const float* __restrict__ wq, const float* __restrict__ wk,
                                              const float* __restrict__ wv, const float* __restrict__ wp,
                                              ushort* __restrict__ wbf,
                                              const float* __restrict__ x, float* __restrict__ pstat){
  if (blockIdx.x >= 256){
    int idx = (blockIdx.x - 256) * 256 + threadIdx.x;
    const float* srcs[4] = {wq, wk, wv, wp};
    #pragma unroll
    for (int m = 0; m < 4; m++){
      float4 v = reinterpret_cast<const float4*>(srcs[m])[idx];
      ushort4 o; o.x = f2bf(v.x); o.y = f2bf(v.y); o.z = f2bf(v.z); o.w = f2bf(v.w);
      reinterpret_cast<ushort4*>(wbf + (size_t)m * CC * CC)[idx] = o;
    }
    return;
  }
  int blk = blockIdx.x;   // 0..255, chunk of 16384 floats
  const float* p = x + (size_t)blk * 16384;
  float s = 0.f, ss = 0.f;
  for (int i = threadIdx.x; i < 4096; i += 256){
    float4 v = reinterpret_cast<const float4*>(p)[i];
    s  += v.x + v.y + v.z + v.w;
    ss += v.x*v.x + v.y*v.y + v.z*v.z + v.w*v.w;
  }
  #pragma unroll
  for (int off = 32; off; off >>= 1){ s += __shfl_down(s, off); ss += __shfl_down(ss, off); }
  __shared__ float rs_[4], rss_[4];
  int w = threadIdx.x >> 6, lane = threadIdx.x & 63;
  if (lane == 0){ rs_[w] = s; rss_[w] = ss; }
  __syncthreads();
  if (threadIdx.x == 0){
    pstat[blk * 2 + 0] = rs_[0] + rs_[1] + rs_[2] + rs_[3];
    pstat[blk * 2 + 1] = rss_[0] + rss_[1] + rss_[2] + rss_[3];
  }
}

// ---------------- GN apply + transpose, stats stage2 folded ----------------
__global__ __launch_bounds__(256) void k_gn_apply(const float* __restrict__ x, const float* __restrict__ gsc,
                                                  const float* __restrict__ gbi, const float* __restrict__ pstat,
                                                  ushort* __restrict__ hf){
  __shared__ ushort tr[32][520];
  __shared__ float stl[64];   // 32 groups x {mean, rstd} for this b
  int b = blockIdx.y;
  int nb = blockIdx.x * 32;
  int t = threadIdx.x;
  if (t < 32){
    float s = 0.f, ss = 0.f;
    #pragma unroll
    for (int k = 0; k < 4; k++){
      s  += pstat[(b * 128 + t * 4 + k) * 2 + 0];
      ss += pstat[(b * 128 + t * 4 + k) * 2 + 1];
    }
    float inv = 1.0f / (16.0f * NN);
    float mean = s * inv;
    float var = ss * inv - mean * mean;
    stl[t * 2 + 0] = mean;
    stl[t * 2 + 1] = rsqrtf(var + EPSV);
  }
  __syncthreads();
  int n = t & 31, cr = t >> 5;
  const float* xb = x + (size_t)b * CC * NN;
  for (int c0 = 0; c0 < CC; c0 += 8){
    int c = c0 + cr;
    float mean = stl[(c >> 4) * 2 + 0];
    float rstd = stl[(c >> 4) * 2 + 1];
    float v = xb[(size_t)c * NN + nb + n];
    tr[n][c] = f2bf((v - mean) * rstd * gsc[c] + gbi[c]);
  }
  __syncthreads();
  ushort* out = hf + ((size_t)b * NN + nb) * CC;
  int c8 = (t & 63) * 8;
  int nrow0 = t >> 6;
  #pragma unroll
  for (int i = 0; i < 8; i++){
    int nr = nrow0 + i * 4;
    *reinterpret_cast<s16x8*>(&out[(size_t)nr * CC + c8]) =
      *reinterpret_cast<const s16x8*>(&tr[nr][c8]);
  }
}

// ---------------- fused QKV GEMM v2: 64o x 128n tile, BK=32, dbuf gload_lds ----------------
__global__ __launch_bounds__(256, 3) void k_gemm_qkv2(const ushort* __restrict__ W, const ushort* __restrict__ Bt,
                                                      const float* __restrict__ bq, const float* __restrict__ bk,
                                                      const float* __restrict__ bv,
                                                      ushort* __restrict__ qo, ushort* __restrict__ ko,
                                                      ushort* __restrict__ vo, float rs){
  __shared__ __align__(16) char smem[40960];
  __shared__ float bl[3][64];
  int b = blockIdx.z, ob = blockIdx.y * 64, nb = blockIdx.x * 128;
  int t = threadIdx.x, w = t >> 6, l = t & 63;
  int lr = l & 15, lk = l >> 4;
  int wo = (w >> 1) * 32, wn = (w & 1) * 64;
  if (t < 64){ bl[0][t] = bq[ob + t]; bl[1][t] = bk[ob + t]; bl[2][t] = bv[ob + t]; }
  const ushort* Bp = Bt + ((size_t)b * NN + nb) * CC;
  const ushort* Wp = W + (size_t)ob * CC;
  int srow = l >> 2;
  int schunk = (l & 3) ^ ((l >> 2) & 3) ^ ((l >> 4) & 3);
  int xs = (lk ^ (lr & 3) ^ ((lr >> 2) & 3)) * 8;

#define STAGE_QKV(BUF, K0)                                                               \
  {                                                                                      \
    ushort* As_ = (ushort*)(smem + (BUF) * 20480);                                       \
    ushort* Bs_ = As_ + 6144;                                                            \
    _Pragma("unroll")                                                                    \
    for (int tt = 0; tt < 5; tt++){                                                      \
      int inst = w * 5 + tt;                                                             \
      if (inst < 12){                                                                    \
        int m = inst >> 2, sub = inst & 3;                                               \
        const ushort* src = Wp + (size_t)m * CC * CC + (size_t)(sub * 16 + srow) * CC + (K0) + schunk * 8; \
        GLOAD_LDS16(src, As_ + m * 2048 + sub * 512);                                    \
      } else {                                                                           \
        int q = inst - 12;                                                               \
        const ushort* src = Bp + (size_t)(q * 16 + srow) * CC + (K0) + schunk * 8;       \
        GLOAD_LDS16(src, Bs_ + q * 512);                                                 \
      }                                                                                  \
    }                                                                                    \
  }

  f32x4 acc[3][2][4] = {};
  STAGE_QKV(0, 0)
  __syncthreads();
  for (int s16 = 0; s16 < 16; s16++){
    if (s16 < 15) STAGE_QKV((s16 + 1) & 1, (s16 + 1) * 32)
    const ushort* As = (const ushort*)(smem + (s16 & 1) * 20480);
    const ushort* Bs = As + 6144;
    s16x8 bf[4];
    #pragma unroll
    for (int sn = 0; sn < 4; sn++)
      bf[sn] = *(const s16x8*)&Bs[(wn + sn * 16 + lr) * 32 + xs];
    #pragma unroll
    for (int m = 0; m < 3; m++){
      s16x8 a0 = *(const s16x8*)&As[m * 2048 + (wo + lr) * 32 + xs];
      s16x8 a1 = *(const s16x8*)&As[m * 2048 + (wo + 16 + lr) * 32 + xs];
      #pragma unroll
      for (int sn = 0; sn < 4; sn++){
        acc[m][0][sn] = mfma16(a0, bf[sn], acc[m][0][sn]);
        acc[m][1][sn] = mfma16(a1, bf[sn], acc[m][1][sn]);
      }
    }
    __syncthreads();
  }
#undef STAGE_QKV
  #pragma unroll
  for (int m = 0; m < 2; m++){
    ushort* dst = (m == 0) ? qo : ko;
    float scl = (m == 0) ? rs : 1.0f;
    #pragma unroll
    for (int so = 0; so < 2; so++)
      #pragma unroll
      for (int sn = 0; sn < 4; sn++){
        int o0 = wo + so * 16 + lk * 4;
        int n  = nb + wn + sn * 16 + lr;
        s16x4 pv;
        #pragma unroll
        for (int r = 0; r < 4; r++) pv[r] = f2bfs((acc[m][so][sn][r] + bl[m][o0 + r]) * scl);
        *reinterpret_cast<s16x4*>(&dst[((size_t)b * NN + n) * CC + ob + o0]) = pv;
      }
  }
  ushort* Ve = (ushort*)smem;   // [64][136]
  #pragma unroll
  for (int so = 0; so < 2; so++)
    #pragma unroll
    for (int sn = 0; sn < 4; sn++){
      int o0 = wo + so * 16 + lk * 4;
      int ncl = wn + sn * 16 + lr;
      #pragma unroll
      for (int r = 0; r < 4; r++) Ve[(o0 + r) * 136 + ncl] = f2bf(acc[2][so][sn][r] + bl[2][o0 + r]);
    }
  __syncthreads();
  {
    int row = t >> 2, cs = (t & 3) * 32;
    ushort* dst = &vo[((size_t)b * CC + ob + row) * NN + nb + cs];
    #pragma unroll
    for (int k = 0; k < 4; k++)
      *(s16x8*)&dst[k * 8] = *(const s16x8*)&Ve[row * 136 + cs + k * 8];
  }
}

// ---------------- S GEMM v6: 256x256, BK=64, 4-phase interleaved schedule ----------------
__global__ __launch_bounds__(512, 2) void k_gemm_s(const ushort* __restrict__ qt, const ushort* __restrict__ kt,
                                                   ushort* __restrict__ P, float* __restrict__ part){
  extern __shared__ __align__(16) char smem[];   // Kbuf[2][32KB] @0, Qbuf[2][32KB] @64KB
  int lin = blockIdx.x + 16 * blockIdx.y + 256 * blockIdx.z;   // 0..511
  int tt0 = (lin & 7) * 64 + (lin >> 3);
  int jblk = tt0 & 15;
  int pair = tt0 >> 4;
  int b = pair >> 4;
  int j0 = jblk * 256, i0 = (pair & 15) * 256;
  int t = threadIdx.x, w = t >> 6, l = t & 63;
  int lr = l & 15, lk = l >> 4;
  int wj2 = w >> 2, wi4 = w & 3;
  const ushort* kb = kt + ((size_t)b * NN + j0) * CC;
  const ushort* qb = qt + ((size_t)b * NN + i0) * CC;
  int srow = l >> 3;
  int schunk = (l & 7) ^ srow;

#define STAGE_KH(BUF, K0, H)                                                      \
  {                                                                               \
    ushort* D = (ushort*)(smem + (BUF) * 32768);                                  \
    _Pragma("unroll")                                                             \
    for (int tt = 0; tt < 2; tt++){                                               \
      int g = (H) * 16 + w * 2 + tt;                                              \
      const ushort* src = kb + (size_t)(g * 8 + srow) * CC + (K0) + schunk * 8;   \
      GLOAD_LDS16(src, D + g * 512);                                              \
    }                                                                             \
  }
#define STAGE_QH(BUF, K0, H)                                                      \
  {                                                                               \
    ushort* D = (ushort*)(smem + 65536 + (BUF) * 32768);                          \
    _Pragma("unroll")                                                             \
    for (int tt = 0; tt < 2; tt++){                                               \
      int g = (H) * 16 + w * 2 + tt;                                              \
      const ushort* src = qb + (size_t)(g * 8 + srow) * CC + (K0) + schunk * 8;   \
      GLOAD_LDS16(src, D + g * 512);                                              \
    }                                                                             \
  }
#define PHASE(SJ, STAGE_CODE)                                                     \
  {                                                                               \
    s16x8 a00 = *(const s16x8*)&Ks[(wj2 * 128 + (SJ) * 16 + lr) * 64 + xs0];      \
    s16x8 a01 = *(const s16x8*)&Ks[(wj2 * 128 + (SJ) * 16 + lr) * 64 + xs1];      \
    s16x8 a10 = *(const s16x8*)&Ks[(wj2 * 128 + ((SJ) + 1) * 16 + lr) * 64 + xs0];\
    s16x8 a11 = *(const s16x8*)&Ks[(wj2 * 128 + ((SJ) + 1) * 16 + lr) * 64 + xs1];\
    STAGE_CODE                                                                    \
    __builtin_amdgcn_s_barrier();                                                 \
    asm volatile("s_waitcnt lgkmcnt(0)" ::: "memory");                            \
    __builtin_amdgcn_sched_barrier(0);                                            \
    __builtin_amdgcn_s_setprio(1);                                                \
    _Pragma("unroll")                                                             \
    for (int si = 0; si < 4; si++){                                               \
      acc[SJ][si]       = mfma16(a00, bq[si][0], acc[SJ][si]);                    \
      acc[SJ][si]       = mfma16(a01, bq[si][1], acc[SJ][si]);                    \
      acc[(SJ) + 1][si] = mfma16(a10, bq[si][0], acc[(SJ) + 1][si]);              \
      acc[(SJ) + 1][si] = mfma16(a11, bq[si][1], acc[(SJ) + 1][si]);              \
    }                                                                             \
    __builtin_amdgcn_s_setprio(0);                                                \
    __builtin_amdgcn_s_barrier();                                                 \
  }

  f32x4 acc[8][4] = {};
  STAGE_KH(0, 0, 0)
  STAGE_KH(0, 0, 1)
  STAGE_QH(0, 0, 0)
  STAGE_QH(0, 0, 1)
  STAGE_QH(1, 64, 0)
  STAGE_QH(1, 64, 1)
  #pragma unroll
  for (int s8 = 0; s8 < 8; s8++){
    const int tau = s8 & 1;
    const ushort* Ks = (const ushort*)(smem + tau * 32768);
    const ushort* Qs = (const ushort*)(smem + 65536 + tau * 32768);
    if (s8 < 7){ asm volatile("s_waitcnt vmcnt(4)" ::: "memory"); }
    else       { asm volatile("s_waitcnt vmcnt(0)" ::: "memory"); }
    __builtin_amdgcn_s_barrier();
    __builtin_amdgcn_sched_barrier(0);
    int xs0 = (lk ^ (lr & 7)) * 8;
    int xs1 = ((4 + lk) ^ (lr & 7)) * 8;
    s16x8 bq[4][2];
    #pragma unroll
    for (int si = 0; si < 4; si++){
      bq[si][0] = *(const s16x8*)&Qs[(wi4 * 64 + si * 16 + lr) * 64 + xs0];
      bq[si][1] = *(const s16x8*)&Qs[(wi4 * 64 + si * 16 + lr) * 64 + xs1];
    }
    PHASE(0, if (s8 < 7) STAGE_KH(tau ^ 1, (s8 + 1) * 64, 0))
    PHASE(2, if (s8 < 7) STAGE_KH(tau ^ 1, (s8 + 1) * 64, 1))
    PHASE(4, if (s8 < 6) STAGE_QH(tau, (s8 + 2) * 64, 0))
    PHASE(6, if (s8 < 6) STAGE_QH(tau, (s8 + 2) * 64, 1))
  }
#undef PHASE
#undef STAGE_KH
#undef STAGE_QH
  ushort* Pe = (ushort*)smem;   // [128 i][264 j] per pass
  float rsum[4] = {0.f, 0.f, 0.f, 0.f};
  #pragma unroll
  for (int pass = 0; pass < 2; pass++){
    if ((wi4 >> 1) == pass){
      #pragma unroll
      for (int sj = 0; sj < 8; sj++)
        #pragma unroll
        for (int si = 0; si < 4; si++){
          int il = (wi4 & 1) * 64 + si * 16 + lr;
          int jl = wj2 * 128 + sj * 16 + lk * 4;
          s16x4 pk;
          #pragma unroll
          for (int r = 0; r < 4; r++){
            float e = __builtin_amdgcn_exp2f(acc[sj][si][r]);
            pk[r] = f2bfs(e);
            rsum[si] += e;
          }
          *(s16x4*)&Pe[il * 264 + jl] = pk;
        }
    }
    __syncthreads();
    {
      int row = t >> 2, cs = (t & 3) * 64;
      ushort* dst = P + ((size_t)b * NN + i0 + pass * 128 + row) * NN + j0 + cs;
      #pragma unroll
      for (int k = 0; k < 8; k++)
        *(s16x8*)&dst[k * 8] = *(const s16x8*)&Pe[row * 264 + cs + k * 8];
    }
    __syncthreads();
  }
  #pragma unroll
  for (int si = 0; si < 4; si++){
    float s = rsum[si];
    s += __shfl_xor(s, 16);
    s += __shfl_xor(s, 32);
    if (lk == 0){
      int il = wi4 * 64 + si * 16 + lr;
      part[((size_t)b * NN + i0 + il) * 32 + jblk * 2 + wj2] = s;
    }
  }
}

// ---------------- O GEMM v4: 128i x 128c, 2-phase interleave, counted vmcnt(2), rowsum folded ----------------
__global__ __launch_bounds__(512) void k_gemm_o(const ushort* __restrict__ P, const ushort* __restrict__ vv,
                                                const float* __restrict__ part, ushort* __restrict__ ot){
  __shared__ __align__(16) char smem[65536];   // Vs[2][16KB] @0, Ps[2][16KB] @32KB
  int lin = blockIdx.x + 4 * blockIdx.y + 128 * blockIdx.z;    // 0..255
  int tt0 = (lin & 7) * 32 + (lin >> 3);
  int cblk = tt0 & 3;
  int ib   = tt0 >> 2;
  int b = ib >> 5;
  int c0 = cblk * 128, i0 = (ib & 31) * 128;
  int t = threadIdx.x, w = t >> 6, l = t & 63;
  int lr = l & 15, lk = l >> 4;
  int wi2 = w >> 2, wc4 = w & 3;
  const ushort* vb = vv + ((size_t)b * CC + c0) * NN;
  const ushort* pb = P + ((size_t)b * NN + i0) * NN;
  int srow = l >> 3;
  int schunk = (l & 7) ^ srow;

#define STAGE_V(BUF, K0)                                                          \
  {                                                                               \
    ushort* D = (ushort*)(smem + (BUF) * 16384);                                  \
    _Pragma("unroll")                                                             \
    for (int tt = 0; tt < 2; tt++){                                               \
      int g = w * 2 + tt;                                                         \
      const ushort* src = vb + (size_t)(g * 8 + srow) * NN + (K0) + schunk * 8;   \
      GLOAD_LDS16(src, D + g * 512);                                              \
    }                                                                             \
  }
#define STAGE_P(BUF, K0)                                                          \
  {                                                                               \
    ushort* D = (ushort*)(smem + 32768 + (BUF) * 16384);                          \
    _Pragma("unroll")                                                             \
    for (int tt = 0; tt < 2; tt++){                                               \
      int g = w * 2 + tt;                                                         \
      const ushort* src = pb + (size_t)(g * 8 + srow) * NN + (K0) + schunk * 8;   \
      GLOAD_LDS16(src, D + g * 512);                                              \
    }                                                                             \
  }

  f32x4 acc[2][4] = {};   // [sc][si]
  STAGE_V(0, 0)
  STAGE_P(0, 0)
  STAGE_P(1, 64)
  for (int s64 = 0; s64 < 64; s64++){
    const int tau = s64 & 1;
    const ushort* Vs = (const ushort*)(smem + tau * 16384);
    const ushort* Ps = (const ushort*)(smem + 32768 + tau * 16384);
    if (s64 < 63){ asm volatile("s_waitcnt vmcnt(2)" ::: "memory"); }
    else         { asm volatile("s_waitcnt vmcnt(0)" ::: "memory"); }
    __builtin_amdgcn_s_barrier();
    __builtin_amdgcn_sched_barrier(0);
    int xs0 = (lk ^ (lr & 7)) * 8;
    int xs1 = ((4 + lk) ^ (lr & 7)) * 8;
    s16x8 bf[4][2];
    #pragma unroll
    for (int si = 0; si < 4; si++){
      bf[si][0] = *(const s16x8*)&Ps[(wi2 * 64 + si * 16 + lr) * 64 + xs0];
      bf[si][1] = *(const s16x8*)&Ps[(wi2 * 64 + si * 16 + lr) * 64 + xs1];
    }
    // ph0: V kk0 + stage V(s+1)
    {
      s16x8 af0 = *(const s16x8*)&Vs[(wc4 * 32 + lr) * 64 + xs0];
      s16x8 af1 = *(const s16x8*)&Vs[(wc4 * 32 + 16 + lr) * 64 + xs0];
      if (s64 < 63) STAGE_V(tau ^ 1, (s64 + 1) * 64)
      __builtin_amdgcn_s_barrier();
      asm volatile("s_waitcnt lgkmcnt(0)" ::: "memory");
      __builtin_amdgcn_sched_barrier(0);
      __builtin_amdgcn_s_setprio(1);
      #pragma unroll
      for (int si = 0; si < 4; si++){
        acc[0][si] = mfma16(af0, bf[si][0], acc[0][si]);
        acc[1][si] = mfma16(af1, bf[si][0], acc[1][si]);
      }
      __builtin_amdgcn_s_setprio(0);
      __builtin_amdgcn_s_barrier();
    }
    // ph1: V kk1 + stage P(s+2) into freed pbuf tau
    {
      s16x8 af0 = *(const s16x8*)&Vs[(wc4 * 32 + lr) * 64 + xs1];
      s16x8 af1 = *(const s16x8*)&Vs[(wc4 * 32 + 16 + lr) * 64 + xs1];
      if (s64 < 62) STAGE_P(tau, (s64 + 2) * 64)
      __builtin_amdgcn_s_barrier();
      asm volatile("s_waitcnt lgkmcnt(0)" ::: "memory");
      __builtin_amdgcn_sched_barrier(0);
      __builtin_amdgcn_s_setprio(1);
      #pragma unroll
      for (int si = 0; si < 4; si++){
        acc[0][si] = mfma16(af0, bf[si][1], acc[0][si]);
        acc[1][si] = mfma16(af1, bf[si][1], acc[1][si]);
      }
      __builtin_amdgcn_s_setprio(0);
      __builtin_amdgcn_s_barrier();
    }
  }
#undef STAGE_V
#undef STAGE_P
  // folded row-sum: linv for this block's 128 i rows
  ushort* Oe = (ushort*)smem;                 // [128 i][136 c] = 34816 B
  float* linv_lds = (float*)(smem + 34816);   // 512 B
  if (t < 128){
    const float* pp = part + ((size_t)b * NN + i0 + t) * 32;
    float s = 0.f;
    #pragma unroll
    for (int k = 0; k < 32; k++) s += pp[k];
    linv_lds[t] = 1.0f / s;
  }
  __syncthreads();
  #pragma unroll
  for (int si = 0; si < 4; si++){
    int il = wi2 * 64 + si * 16 + lr;
    float li = linv_lds[il];
    #pragma unroll
    for (int sc = 0; sc < 2; sc++){
      int cl = wc4 * 32 + sc * 16 + lk * 4;
      s16x4 pk;
      #pragma unroll
      for (int r = 0; r < 4; r++) pk[r] = f2bfs(acc[sc][si][r] * li);
      *(s16x4*)&Oe[il * 136 + cl] = pk;
    }
  }
  __syncthreads();
  {
    int row = t >> 2, cs = (t & 3) * 32;
    ushort* dst = ot + ((size_t)b * NN + i0 + row) * CC + c0 + cs;
    #pragma unroll
    for (int k = 0; k < 4; k++)
      *(s16x8*)&dst[k * 8] = *(const s16x8*)&Oe[row * 136 + cs + k * 8];
  }
}

// ---------------- proj GEMM v2: 64o x 128n, BK=32, dbuf gload_lds; fp32 out + residual ----------------
__global__ __launch_bounds__(256, 3) void k_gemm_proj2(const ushort* __restrict__ A, const ushort* __restrict__ Bt,
                                                       const float* __restrict__ bias, float* __restrict__ o32,
                                                       const float* __restrict__ xres){
  __shared__ __align__(16) char smem[34048];
  __shared__ float bl[64];
  int b = blockIdx.z, ob = blockIdx.y * 64, nb = blockIdx.x * 128;
  int t = threadIdx.x, w = t >> 6, l = t & 63;
  int lr = l & 15, lk = l >> 4;
  int wo = (w >> 1) * 32, wn = (w & 1) * 64;
  if (t < 64) bl[t] = bias[ob + t];
  const ushort* Bp = Bt + ((size_t)b * NN + nb) * CC;
  const ushort* Ap = A + (size_t)ob * CC;
  int srow = l >> 2;
  int schunk = (l & 3) ^ ((l >> 2) & 3) ^ ((l >> 4) & 3);
  int xs = (lk ^ (lr & 3) ^ ((lr >> 2) & 3)) * 8;

#define STAGE_P2(BUF, K0)                                                         \
  {                                                                               \
    ushort* As_ = (ushort*)(smem + (BUF) * 12288);                                \
    ushort* Bs_ = As_ + 2048;                                                     \
    _Pragma("unroll")                                                             \
    for (int tt = 0; tt < 3; tt++){                                               \
      int inst = w * 3 + tt;                                                      \
      if (inst < 4){                                                              \
        const ushort* src = Ap + (size_t)(inst * 16 + srow) * CC + (K0) + schunk * 8; \
        GLOAD_LDS16(src, As_ + inst * 512);                                       \
      } else {                                                                    \
        int q = inst - 4;                                                         \
        const ushort* src = Bp + (size_t)(q * 16 + srow) * CC + (K0) + schunk * 8; \
        GLOAD_LDS16(src, Bs_ + q * 512);                                          \
      }                                                                           \
    }                                                                             \
  }

  f32x4 acc[2][4] = {};
  STAGE_P2(0, 0)
  __syncthreads();
  for (int s16 = 0; s16 < 16; s16++){
    if (s16 < 15) STAGE_P2((s16 + 1) & 1, (s16 + 1) * 32)
    const ushort* As = (const ushort*)(smem + (s16 & 1) * 12288);
    const ushort* Bs = As + 2048;
    s16x8 a0 = *(const s16x8*)&As[(wo + lr) * 32 + xs];
    s16x8 a1 = *(const s16x8*)&As[(wo + 16 + lr) * 32 + xs];
    #pragma unroll
    for (int sn = 0; sn < 4; sn++){
      s16x8 bf = *(const s16x8*)&Bs[(wn + sn * 16 + lr) * 32 + xs];
      acc[0][sn] = mfma16(a0, bf, acc[0][sn]);
      acc[1][sn] = mfma16(a1, bf, acc[1][sn]);
    }
    __syncthreads();
  }
#undef STAGE_P2
  float* trf = (float*)smem;   // [64][133]
  #pragma unroll
  for (int so = 0; so < 2; so++)
    #pragma unroll
    for (int sn = 0; sn < 4; sn++){
      int o0 = wo + so * 16 + lk * 4;
      int ncl = wn + sn * 16 + lr;
      #pragma unroll
      for (int r = 0; r < 4; r++) trf[(o0 + r) * 133 + ncl] = acc[so][sn][r] + bl[o0 + r];
    }
  __syncthreads();
  {
    int row = t >> 2, cs = (t & 3) * 32;
    size_t base = ((size_t)b * CC + ob + row) * NN + nb + cs;
    #pragma unroll
    for (int q = 0; q < 8; q++){
      float4 xv = *reinterpret_cast<const float4*>(&xres[base + q * 4]);
      float4 ov;
      ov.x = xv.x + trf[row * 133 + cs + q * 4 + 0];
      ov.y = xv.y + trf[row * 133 + cs + q * 4 + 1];
      ov.z = xv.z + trf[row * 133 + cs + q * 4 + 2];
      ov.w = xv.w + trf[row * 133 + cs + q * 4 + 3];
      *reinterpret_cast<float4*>(&o32[base + q * 4]) = ov;
    }
  }
}

extern "C" void kernel_launch(void* const* d_in, const int* in_sizes, int n_in,
                              void* d_out, int out_size, void* d_ws, size_t ws_size,
                              hipStream_t stream){
  const float* x   = (const float*)d_in[0];
  const float* gsc = (const float*)d_in[1];
  const float* gbi = (const float*)d_in[2];
  const float* wq  = (const float*)d_in[3];
  const float* bq  = (const float*)d_in[4];
  const float* wk  = (const float*)d_in[5];
  const float* bk  = (const float*)d_in[6];
  const float* wv  = (const float*)d_in[7];
  const float* bv  = (const float*)d_in[8];
  const float* wp  = (const float*)d_in[9];
  const float* bp  = (const float*)d_in[10];
  char* ws = (char*)d_ws;
  const size_t MB = 1024 * 1024;
  // workspace map:
  ushort* wbf  = (ushort*)ws;                    // [0,2MB): bf16 weights
  ushort* qtb  = (ushort*)(ws + 2 * MB);         // [2,10): q^T; DEAD after gemm_s -> reused as attn-out ot
  ushort* ktb  = (ushort*)(ws + 10 * MB);        // [10,18): k^T
  ushort* vvb  = (ushort*)(ws + 18 * MB);        // [18,26): v [b][c][n]
  ushort* hfb  = (ushort*)(ws + 26 * MB);        // [26,34): hf^T; DEAD after qkv2 -> part lives here
  ushort* Pbuf = (ushort*)(ws + 34 * MB);        // [34,98): P = exp2(S) bf16
  float* pstat = (float*)(ws + 98 * MB);         // 2 KB GN partial stats
  float* part  = (float*)(ws + 26 * MB);         // 1MB row-sum partials (dead-hf window)
  ushort* otb  = qtb;                            // attn-out in dead q^T region

  const float rs = 0.044194173824159216f * 1.4426950408889634f;

  k_prep<<<512, 256, 0, stream>>>(wq, wk, wv, wp, wbf, x, pstat);
  k_gn_apply<<<dim3(128, 2, 1), 256, 0, stream>>>(x, gsc, gbi, pstat, hfb);
  k_gemm_qkv2<<<dim3(32, 8, 2), 256, 0, stream>>>(wbf, hfb, bq, bk, bv, qtb, ktb, vvb, rs);
  k_gemm_s<<<dim3(16, 16, 2), 512, 131072, stream>>>(qtb, ktb, Pbuf, part);
  k_gemm_o<<<dim3(4, 32, 2), 512, 0, stream>>>(Pbuf, vvb, part, otb);
  k_gemm_proj2<<<dim3(32, 8, 2), 256, 0, stream>>>(wbf + 3 * CC * CC, otb, bp, (float*)d_out, x);
}